// Round 7
// baseline (1051.671 us; speedup 1.0000x reference)
//
#include <hip/hip_runtime.h>
#include <stdint.h>
#include <math.h>

// Problem constants (fixed by reference setup_inputs)
#define B_SZ   32
#define T_LEN  2048
#define DIN    512
#define DD     512
#define M_TOT  (B_SZ * T_LEN)   // 65536 rows
#define BM     64               // fused-kernel row tile
#define WSZ    ((size_t)DD * DD)

typedef unsigned short u16;
typedef __attribute__((ext_vector_type(8))) short short8;
typedef __attribute__((ext_vector_type(4))) float f32x4;
typedef __attribute__((ext_vector_type(4))) unsigned int u32x4;

// ---------------------------------------------------------------------------
// fp32 -> bf16 round-to-nearest-even (scalar, for wt_all)
// ---------------------------------------------------------------------------
__device__ __forceinline__ u16 f2bf(float f) {
  uint32_t u = __float_as_uint(f);
  uint32_t r = (u + 0x7FFFu + ((u >> 16) & 1u)) >> 16;
  return (u16)r;
}

// packed f32x2 -> bf16x2 (RTNE), gfx950 hw instruction (no builtin)
__device__ __forceinline__ uint32_t cvtpk(float lo, float hi) {
  uint32_t r;
  asm("v_cvt_pk_bf16_f32 %0, %1, %2" : "=v"(r) : "v"(lo), "v"(hi));
  return r;
}

// async global->LDS, 16B per lane
typedef const void __attribute__((address_space(1)))* as1cp;
typedef void __attribute__((address_space(3)))* as3p;
__device__ __forceinline__ void async16(const void* g, void* l) {
  __builtin_amdgcn_global_load_lds((as1cp)(uintptr_t)g,
                                   (as3p)(uint32_t)(uintptr_t)l, 16, 0, 0);
}

__device__ __forceinline__ float sigm_fast(float x) {
  return 1.f / (1.f + __expf(-x));
}
__device__ __forceinline__ float tanh_fast(float x) {
  return 1.f - 2.f / (1.f + __expf(2.f * x));
}

// ---------------------------------------------------------------------------
// Threefry-2x32 (20 rounds), bit-exact vs JAX's threefry2x32 primitive.
// ---------------------------------------------------------------------------
__device__ __forceinline__ uint32_t rotl32(uint32_t x, int n) {
  return (x << n) | (x >> (32 - n));
}

__device__ __forceinline__ void threefry2x32(uint32_t k0, uint32_t k1,
                                             uint32_t x0, uint32_t x1,
                                             uint32_t& o0, uint32_t& o1) {
  const uint32_t ks0 = k0, ks1 = k1, ks2 = k0 ^ k1 ^ 0x1BD11BDAu;
  uint32_t v0 = x0 + ks0, v1 = x1 + ks1;
#define TF_R(r) { v0 += v1; v1 = rotl32(v1, (r)); v1 ^= v0; }
  TF_R(13) TF_R(15) TF_R(26) TF_R(6)
  v0 += ks1; v1 += ks2 + 1u;
  TF_R(17) TF_R(29) TF_R(16) TF_R(24)
  v0 += ks2; v1 += ks0 + 2u;
  TF_R(13) TF_R(15) TF_R(26) TF_R(6)
  v0 += ks0; v1 += ks1 + 3u;
  TF_R(17) TF_R(29) TF_R(16) TF_R(24)
  v0 += ks1; v1 += ks2 + 4u;
  TF_R(13) TF_R(15) TF_R(26) TF_R(6)
  v0 += ks2; v1 += ks0 + 5u;
#undef TF_R
  o0 = v0; o1 = v1;
}

// ---------------------------------------------------------------------------
// Noise under JAX_ENABLE_X64=1 + partitionable threefry (verified round 3):
//   split (foldlike): keys[j] = threefry(key, (0, j))
//   bernoulli(p: python float -> f64): 64-bit draw bits64[i]=(b1<<32)|b2,
//   counter (0,i); u<0.25 <=> b1<0x40000000 ; u<0.75 <=> b1<0xC0000000
// ---------------------------------------------------------------------------
__global__ void noise_kernel(float* __restrict__ noise_i, float* __restrict__ noise_s) {
  int i = blockIdx.x * blockDim.x + threadIdx.x;
  if (i >= B_SZ * DIN) return;
  uint32_t k1a, k1b, k2a, k2b;
  threefry2x32(0u, 42u, 0u, 0u, k1a, k1b);
  threefry2x32(0u, 42u, 0u, 1u, k2a, k2b);
  uint32_t b1, b2;
  threefry2x32(k1a, k1b, 0u, (uint32_t)i, b1, b2);
  noise_i[i] = (b1 < 0x40000000u) ? 4.0f : 0.0f;
  threefry2x32(k2a, k2b, 0u, (uint32_t)i, b1, b2);
  noise_s[i] = (b1 < 0xC0000000u) ? (1.0f / 0.75f) : 0.0f;
}

// layer-0 state projections, exact fp32 (t-independent)
__global__ __launch_bounds__(256) void vec0_kernel(
    const float* __restrict__ h0, const float* __restrict__ noise_s,
    const float* __restrict__ rHw, const float* __restrict__ rHb,
    const float* __restrict__ rTw, const float* __restrict__ rTb,
    float* __restrict__ vH0, float* __restrict__ vT0) {
  __shared__ float sdv[DD];
  const int b = blockIdx.x >> 1;
  const int c = (blockIdx.x & 1) * 256 + threadIdx.x;
  for (int k = threadIdx.x; k < DD; k += 256)
    sdv[k] = h0[k] * noise_s[b * DD + k];
  __syncthreads();
  float aH = 0.f, aT = 0.f;
  for (int k = 0; k < DD; ++k) {
    float v = sdv[k];
    aH += v * rHw[(size_t)k * DD + c];
    aT += v * rTw[(size_t)k * DD + c];
  }
  vH0[b * DD + c] = aH + rHb[c];
  vT0[b * DD + c] = aT + rTb[c];
}

// ---------------------------------------------------------------------------
// Transpose+convert all six 512x512 fp32 W[k][n] -> bf16 Wt[n][k].
// Wt order: 0=wH 1=wT 2=r1H 3=r1T 4=r2H 5=r2T
// ---------------------------------------------------------------------------
__global__ __launch_bounds__(256) void wt_all(
    const float* __restrict__ wH, const float* __restrict__ wT,
    const float* __restrict__ rHw, const float* __restrict__ rTw,
    u16* __restrict__ Wt) {
  __shared__ float tile[64][68];
  const int which = blockIdx.x >> 6;
  const float* W;
  switch (which) {
    case 0: W = wH; break;
    case 1: W = wT; break;
    case 2: W = rHw + WSZ; break;
    case 3: W = rTw + WSZ; break;
    case 4: W = rHw + 2 * WSZ; break;
    default: W = rTw + 2 * WSZ; break;
  }
  u16* dst = Wt + (size_t)which * WSZ;
  const int tb = blockIdx.x & 63;
  const int kt = (tb >> 3) * 64;
  const int nt = (tb & 7) * 64;
  const int tid = threadIdx.x;
  {
    int r = tid >> 2;
#pragma unroll
    for (int u = 0; u < 4; ++u) {
      int c = ((tid & 3) + u * 4) * 4;
      float4 v = *(const float4*)(W + (size_t)(kt + r) * DD + nt + c);
      tile[r][c] = v.x; tile[r][c + 1] = v.y; tile[r][c + 2] = v.z; tile[r][c + 3] = v.w;
    }
  }
  __syncthreads();
  {
    int n = tid >> 2, seg = (tid & 3) * 16;
    u16 o[16];
#pragma unroll
    for (int u = 0; u < 16; ++u) o[u] = f2bf(tile[seg + u][n]);
    *(uint4*)(dst + (size_t)(nt + n) * DD + kt + seg) = *(const uint4*)o;
    *(uint4*)(dst + (size_t)(nt + n) * DD + kt + seg + 8) = *(const uint4*)(o + 8);
  }
}

// ---------------------------------------------------------------------------
// FUSED 3-LAYER RHN kernel, v3.
// Round-6 structure, but K-loop register pressure cut below the 256-unified
// ceiling (round 6 spilled ~260 B/thread: FETCH/WRITE both ~260 MB over
// ideal):
//   - SINGLE named W-fragment bank (32 regs, was 64 double-banked); the
//     chunk's 8 global loads are issued first and their ~200cy L2 latency
//     overlaps the A-fragment build (LDS reads + cvtpk) and the co-resident
//     wave's MFMAs.
//   - 32-bit W offsets (int co32[4]) instead of size_t array (-12 regs).
// Numerics byte-identical to round 6 (same op order) -> absmax must stay
// 0.006836; that is the control for the spill theory.
// ---------------------------------------------------------------------------
__global__ __launch_bounds__(512, 2) void fused_rhn(
    const float* __restrict__ seq,   // [65536][512] f32
    const u16* __restrict__ Wt,      // 6 x [512n][512k] bf16
    const float* __restrict__ noise_i,  // [32][512]
    const float* __restrict__ noise_s,  // [32][512]
    const float* __restrict__ vH0,   // [32][512]
    const float* __restrict__ vT0,
    const float* __restrict__ h0,    // [512]
    const float* __restrict__ bH, const float* __restrict__ bT,
    const float* __restrict__ rHb, const float* __restrict__ rTb,
    float* __restrict__ out) {
  __shared__ float S[BM * DD];       // 128 KB, swizzled f32 state tile
  __shared__ float nzi[DD];
  __shared__ float nzs[DD];

  const int tid  = threadIdx.x;      // 0..511
  const int lane = tid & 63, wid = tid >> 6;
  const int m0   = blockIdx.x * BM;
  const int bidx = m0 >> 11;         // batch index (64 | 2048)
  const int q  = lane >> 4, mr = lane & 15;
  const int c0w = wid * 64;          // wave's column base
  const int swm = (mr & 7) << 4;     // frag-read swizzle (row&7 == mr&7)

  // stage noise rows for this batch
  if (tid < DD) {
    nzi[tid] = noise_i[bidx * DD + tid];
    nzs[tid] = noise_s[bidx * DD + tid];
  }
  // stage seq tile as layer-0 A/state: linear LDS dest, pre-swizzled source.
  // granule g: row = g>>7, slot = g&127 holds source k16 = slot ^ (row&7).
#pragma unroll
  for (int t = 0; t < 16; ++t) {
    int g = tid + t * 512;
    int row = g >> 7, slot = g & 127;
    int j16 = slot ^ (row & 7);
    async16(seq + (size_t)(m0 + row) * DD + j16 * 4, (char*)S + (size_t)g * 16);
  }
  __syncthreads();   // drains vmcnt (compiler emits vmcnt(0) before barrier)

  for (int l = 0; l < 3; ++l) {
    const u16* WH = Wt + (size_t)(2 * l) * WSZ;
    const u16* WTm = WH + WSZ;
    const float* nz = (l == 0) ? nzi : nzs;

    f32x4 accH[4][4], accT[4][4];
#pragma unroll
    for (int i = 0; i < 4; ++i)
#pragma unroll
      for (int j = 0; j < 4; ++j) {
        accH[i][j] = (f32x4){0.f, 0.f, 0.f, 0.f};
        accT[i][j] = (f32x4){0.f, 0.f, 0.f, 0.f};
      }

    // 32-bit element offsets into Wt panels (fits: 512 KB panel)
    int co32[4];
#pragma unroll
    for (int nt = 0; nt < 4; ++nt)
      co32[nt] = (c0w + nt * 16 + mr) * DD + q * 8;

#pragma unroll
    for (int kb = 0; kb < 16; ++kb) {
      // 1) issue this chunk's W loads (single bank; latency overlaps A-build)
      short8 whC[4], wtC[4];
#pragma unroll
      for (int nt = 0; nt < 4; ++nt) {
        whC[nt] = *(const short8*)(WH  + co32[nt] + kb * 32);
        wtC[nt] = *(const short8*)(WTm + co32[nt] + kb * 32);
      }
      // 2) build A-frags from swizzled S while W flies
      const int k0 = kb * 32 + q * 8;
      const float4 n0 = *(const float4*)&nz[k0];
      const float4 n1 = *(const float4*)&nz[k0 + 4];
      short8 a[4];
#pragma unroll
      for (int mt = 0; mt < 4; ++mt) {
        const int row = mt * 16 + mr;
        const char* Sb = (const char*)S + (size_t)row * 2048;
        const int kbase = kb * 128 + q * 32;
        float4 v0 = *(const float4*)(Sb + (kbase ^ swm));
        float4 v1 = *(const float4*)(Sb + ((kbase + 16) ^ swm));
        u32x4 pk;
        pk.x = cvtpk(v0.x * n0.x, v0.y * n0.y);
        pk.y = cvtpk(v0.z * n0.z, v0.w * n0.w);
        pk.z = cvtpk(v1.x * n1.x, v1.y * n1.y);
        pk.w = cvtpk(v1.z * n1.z, v1.w * n1.w);
        a[mt] = *(short8*)&pk;
      }
      // 3) MFMA
#pragma unroll
      for (int nt = 0; nt < 4; ++nt) {
#pragma unroll
        for (int mt = 0; mt < 4; ++mt) {
          accH[mt][nt] = __builtin_amdgcn_mfma_f32_16x16x32_bf16(a[mt], whC[nt], accH[mt][nt], 0, 0, 0);
          accT[mt][nt] = __builtin_amdgcn_mfma_f32_16x16x32_bf16(a[mt], wtC[nt], accT[mt][nt], 0, 0, 0);
        }
      }
    }

    // all waves done reading S before we overwrite it
    __syncthreads();

    const float* hbv = (l == 0) ? bH : (rHb + l * DD);
    const float* tbv = (l == 0) ? bT : (rTb + l * DD);
    const int b512 = bidx * DD;
#pragma unroll
    for (int nt = 0; nt < 4; ++nt) {
      const int gc = c0w + nt * 16 + mr;
      float hb = hbv[gc], tb = tbv[gc];
      float h0c = 0.f;
      if (l == 0) {
        hb += vH0[b512 + gc];
        tb += vT0[b512 + gc];
        h0c = h0[gc];
      }
#pragma unroll
      for (int mt = 0; mt < 4; ++mt) {
#pragma unroll
        for (int r = 0; r < 4; ++r) {
          const int row = mt * 16 + q * 4 + r;
          char* Sp = (char*)S + (size_t)row * 2048 + (((unsigned)(gc * 4)) ^ ((row & 7) << 4));
          float sp = (l == 0) ? h0c : *(const float*)Sp;
          float hg = tanh_fast(accH[mt][nt][r] + hb);
          float tg = sigm_fast(accT[mt][nt][r] + tb);
          float sn = (hg - sp) * tg + sp;
          if (l < 2) *(float*)Sp = sn;
          else out[(size_t)(m0 + row) * DD + gc] = sn;
        }
      }
    }
    __syncthreads();   // S update visible before next layer's frag reads
  }
}

// ---------------------------------------------------------------------------
extern "C" void kernel_launch(void* const* d_in, const int* in_sizes, int n_in,
                              void* d_out, int out_size, void* d_ws, size_t ws_size,
                              hipStream_t stream) {
  const float* h0  = (const float*)d_in[0];
  const float* seq = (const float*)d_in[1];
  const float* wH  = (const float*)d_in[2];
  const float* bH  = (const float*)d_in[3];
  const float* wT  = (const float*)d_in[4];
  const float* bT  = (const float*)d_in[5];
  const float* rHw = (const float*)d_in[6];
  const float* rHb = (const float*)d_in[7];
  const float* rTw = (const float*)d_in[8];
  const float* rTb = (const float*)d_in[9];
  float* out = (float*)d_out;

  char* ws = (char*)d_ws;
  float* noise_i = (float*)(ws);                       // 64 KB
  float* noise_s = (float*)(ws + (64 << 10));          // 64 KB
  float* vH0     = (float*)(ws + (128 << 10));         // 64 KB
  float* vT0     = (float*)(ws + (192 << 10));         // 64 KB
  u16* Wt    = (u16*)(ws + (256 << 10));               // 6 x 512 KB

  noise_kernel<<<64, 256, 0, stream>>>(noise_i, noise_s);
  vec0_kernel<<<64, 256, 0, stream>>>(h0, noise_s, rHw, rHb, rTw, rTb, vH0, vT0);
  wt_all<<<384, 256, 0, stream>>>(wH, wT, rHw, rTw, Wt);

  fused_rhn<<<M_TOT / BM, 512, 0, stream>>>(
      seq, Wt, noise_i, noise_s, vH0, vT0, h0, bH, bT, rHb, rTb, out);
}

// Round 9
// 721.938 us; speedup vs baseline: 1.4567x; 1.4567x over previous
//
#include <hip/hip_runtime.h>
#include <stdint.h>
#include <math.h>

// Problem constants (fixed by reference setup_inputs)
#define B_SZ   32
#define T_LEN  2048
#define DIN    512
#define DD     512
#define M_TOT  (B_SZ * T_LEN)   // 65536 rows
#define NTHREADS 256
#define WSZ    ((size_t)DD * DD)

typedef unsigned short u16;
typedef __attribute__((ext_vector_type(8))) short short8;
typedef __attribute__((ext_vector_type(4))) float f32x4;

// ---------------------------------------------------------------------------
// fp32 -> bf16 round-to-nearest-even
// ---------------------------------------------------------------------------
__device__ __forceinline__ u16 f2bf(float f) {
  uint32_t u = __float_as_uint(f);
  uint32_t r = (u + 0x7FFFu + ((u >> 16) & 1u)) >> 16;
  return (u16)r;
}

// async global->LDS, 16B per lane; LDS dest = wave-uniform base + lane*16
typedef const void __attribute__((address_space(1)))* as1cp;
typedef void __attribute__((address_space(3)))* as3p;
__device__ __forceinline__ void async16(const void* g, void* l) {
  __builtin_amdgcn_global_load_lds((as1cp)(uintptr_t)g,
                                   (as3p)(uint32_t)(uintptr_t)l, 16, 0, 0);
}

// ---------------------------------------------------------------------------
// Threefry-2x32 (20 rounds), bit-exact vs JAX's threefry2x32 primitive.
// ---------------------------------------------------------------------------
__device__ __forceinline__ uint32_t rotl32(uint32_t x, int n) {
  return (x << n) | (x >> (32 - n));
}

__device__ __forceinline__ void threefry2x32(uint32_t k0, uint32_t k1,
                                             uint32_t x0, uint32_t x1,
                                             uint32_t& o0, uint32_t& o1) {
  const uint32_t ks0 = k0, ks1 = k1, ks2 = k0 ^ k1 ^ 0x1BD11BDAu;
  uint32_t v0 = x0 + ks0, v1 = x1 + ks1;
#define TF_R(r) { v0 += v1; v1 = rotl32(v1, (r)); v1 ^= v0; }
  TF_R(13) TF_R(15) TF_R(26) TF_R(6)
  v0 += ks1; v1 += ks2 + 1u;
  TF_R(17) TF_R(29) TF_R(16) TF_R(24)
  v0 += ks2; v1 += ks0 + 2u;
  TF_R(13) TF_R(15) TF_R(26) TF_R(6)
  v0 += ks0; v1 += ks1 + 3u;
  TF_R(17) TF_R(29) TF_R(16) TF_R(24)
  v0 += ks1; v1 += ks2 + 4u;
  TF_R(13) TF_R(15) TF_R(26) TF_R(6)
  v0 += ks2; v1 += ks0 + 5u;
#undef TF_R
  o0 = v0; o1 = v1;
}

// ---------------------------------------------------------------------------
// Noise under JAX_ENABLE_X64=1 + partitionable threefry (verified round 3):
//   split (foldlike): keys[j] = threefry(key, (0, j))
//   bernoulli(p: python float -> f64): 64-bit draw bits64[i]=(b1<<32)|b2,
//   counter (0,i); u<0.25 <=> b1<0x40000000 ; u<0.75 <=> b1<0xC0000000
// ---------------------------------------------------------------------------
__global__ void noise_kernel(float* __restrict__ noise_i, float* __restrict__ noise_s) {
  int i = blockIdx.x * blockDim.x + threadIdx.x;
  if (i >= B_SZ * DIN) return;
  uint32_t k1a, k1b, k2a, k2b;
  threefry2x32(0u, 42u, 0u, 0u, k1a, k1b);
  threefry2x32(0u, 42u, 0u, 1u, k2a, k2b);
  uint32_t b1, b2;
  threefry2x32(k1a, k1b, 0u, (uint32_t)i, b1, b2);
  noise_i[i] = (b1 < 0x40000000u) ? 4.0f : 0.0f;
  threefry2x32(k2a, k2b, 0u, (uint32_t)i, b1, b2);
  noise_s[i] = (b1 < 0xC0000000u) ? (1.0f / 0.75f) : 0.0f;
}

// layer-0 state projections, exact fp32 (t-independent)
__global__ __launch_bounds__(256) void vec0_kernel(
    const float* __restrict__ h0, const float* __restrict__ noise_s,
    const float* __restrict__ rHw, const float* __restrict__ rHb,
    const float* __restrict__ rTw, const float* __restrict__ rTb,
    float* __restrict__ vH0, float* __restrict__ vT0) {
  __shared__ float sdv[DD];
  const int b = blockIdx.x >> 1;
  const int c = (blockIdx.x & 1) * 256 + threadIdx.x;
  for (int k = threadIdx.x; k < DD; k += 256)
    sdv[k] = h0[k] * noise_s[b * DD + k];
  __syncthreads();
  float aH = 0.f, aT = 0.f;
  for (int k = 0; k < DD; ++k) {
    float v = sdv[k];
    aH += v * rHw[(size_t)k * DD + c];
    aT += v * rTw[(size_t)k * DD + c];
  }
  vH0[b * DD + c] = aH + rHb[c];
  vT0[b * DD + c] = aT + rTb[c];
}

// ---------------------------------------------------------------------------
// Transpose+convert all six 512x512 fp32 W[k][n] -> bf16 Wt[n][k].
// Wt order: 0=wH 1=wT 2=r1H 3=r1T 4=r2H 5=r2T
// ---------------------------------------------------------------------------
__global__ __launch_bounds__(256) void wt_all(
    const float* __restrict__ wH, const float* __restrict__ wT,
    const float* __restrict__ rHw, const float* __restrict__ rTw,
    u16* __restrict__ Wt) {
  __shared__ float tile[64][68];
  const int which = blockIdx.x >> 6;
  const float* W;
  switch (which) {
    case 0: W = wH; break;
    case 1: W = wT; break;
    case 2: W = rHw + WSZ; break;
    case 3: W = rTw + WSZ; break;
    case 4: W = rHw + 2 * WSZ; break;
    default: W = rTw + 2 * WSZ; break;
  }
  u16* dst = Wt + (size_t)which * WSZ;
  const int tb = blockIdx.x & 63;
  const int kt = (tb >> 3) * 64;
  const int nt = (tb & 7) * 64;
  const int tid = threadIdx.x;
  {
    int r = tid >> 2;
#pragma unroll
    for (int u = 0; u < 4; ++u) {
      int c = ((tid & 3) + u * 4) * 4;
      float4 v = *(const float4*)(W + (size_t)(kt + r) * DD + nt + c);
      tile[r][c] = v.x; tile[r][c + 1] = v.y; tile[r][c + 2] = v.z; tile[r][c + 3] = v.w;
    }
  }
  __syncthreads();
  {
    int n = tid >> 2, seg = (tid & 3) * 16;
    u16 o[16];
#pragma unroll
    for (int u = 0; u < 16; ++u) o[u] = f2bf(tile[seg + u][n]);
    *(uint4*)(dst + (size_t)(nt + n) * DD + kt + seg) = *(const uint4*)o;
    *(uint4*)(dst + (size_t)(nt + n) * DD + kt + seg + 8) = *(const uint4*)(o + 8);
  }
}

// ---------------------------------------------------------------------------
// Xbf[m][k] = bf16(seq[m][k] * noise_i[b][k]);  one thread per 8 elements.
// ---------------------------------------------------------------------------
__global__ __launch_bounds__(256) void xprep(const float* __restrict__ seq,
                                             const float* __restrict__ noise_i,
                                             u16* __restrict__ Xbf) {
  int idx = blockIdx.x * 256 + threadIdx.x;
  int row = idx >> 6;
  int k8 = (idx & 63) * 8;
  int b = row >> 11;
  const float* s = seq + (size_t)row * DIN + k8;
  const float* n = noise_i + b * DIN + k8;
  float4 s0 = *(const float4*)s, s1 = *(const float4*)(s + 4);
  float4 n0 = *(const float4*)n, n1 = *(const float4*)(n + 4);
  u16 o[8];
  o[0] = f2bf(s0.x * n0.x); o[1] = f2bf(s0.y * n0.y);
  o[2] = f2bf(s0.z * n0.z); o[3] = f2bf(s0.w * n0.w);
  o[4] = f2bf(s1.x * n1.x); o[5] = f2bf(s1.y * n1.y);
  o[6] = f2bf(s1.z * n1.z); o[7] = f2bf(s1.w * n1.w);
  *(uint4*)(Xbf + (size_t)idx * 8) = *(const uint4*)o;
}

// ---------------------------------------------------------------------------
// Fused layer GEMM, occupancy-doubled evolution of the round-3 trunk:
//   C_tile 64m x 128c, K=512 in 8 chunks of 64, 4 waves.
//   Wave tile 32m x 64c  -> accH+accT = 64 AGPRs (was 128): unified regs
//   ~130 -> __launch_bounds__(256,3) admits 3 blocks/CU = 12 waves/CU
//   (round 3 was stuck at 2 waves/SIMD, Occupancy 18.6%, latency-bound).
// LDS 40 KB (A 8K | BH 16K | BT 16K), XOR-swizzled exactly as round 3
// (verified 0 bank conflicts). 2-phase barrier K-loop (verified). XCD
// swizzle on bid (verified FETCH win; 4096 % 8 == 0, bijective).
// Epilogue: highway combine, write S (fp32) + SD (bf16) or final out.
// ---------------------------------------------------------------------------
__global__ __launch_bounds__(256, 3) void layer_gemm(
    const u16* __restrict__ Abf,    // [65536][512] bf16 (X' or SD)
    const u16* __restrict__ WtH,    // [512 n][512 k] bf16
    const u16* __restrict__ WtT,
    const float* __restrict__ hbv,  // [512]
    const float* __restrict__ tbv,  // [512]
    const float* __restrict__ vH0,  // [32][512] (layer0) or null
    const float* __restrict__ vT0,
    const float* __restrict__ h0,   // [512]
    const float* __restrict__ noise_s, // [32][512]
    const float* Sprev,             // fp32, null for layer0
    float* Snew,                    // fp32 (layers 0,1)
    u16* __restrict__ SDnew,        // bf16 (layers 0,1)
    float* Out,                     // fp32 (layer2)
    int layer) {
  __shared__ u16 lds[20480];        // A:4096, BH:8192, BT:8192 (40 KiB)
  u16* ldsA  = lds;
  u16* ldsBH = lds + 4096;
  u16* ldsBT = lds + 12288;

  const int tid  = threadIdx.x;
  const int lane = tid & 63, wid = tid >> 6;
  // XCD swizzle: 4096 blocks, 8 XCDs, bijective chunked remap
  const int bid  = (blockIdx.x & 7) * 512 + (blockIdx.x >> 3);
  const int m0   = (bid >> 2) * 64;     // 1024 m-tiles
  const int c0   = (bid & 3) * 128;     // 4 c-tiles
  const int bidx = m0 >> 11;            // batch index (tile never crosses b)
  const int q  = lane >> 4, mr = lane & 15;
  const int wqm = wid >> 1, wqn = wid & 1;  // rows-half, cols-half

  // Per-lane staging addresses. LDS slot s (16B) holds granule
  // (row = s>>3, k8 = (s&7) ^ (row&7)) of the current k-chunk.
  // A: 512 granules (2/thread); BH/BT: 1024 granules (4/thread).
  const u16* gA[2]; const u16* gBH[4]; const u16* gBT[4];
  u16* lA[2]; u16* lBH[4]; u16* lBT[4];
#pragma unroll
  for (int t = 0; t < 2; ++t) {
    int s  = tid + t * 256;
    int rm = s >> 3;
    int k8 = (s & 7) ^ (rm & 7);
    gA[t] = Abf + (size_t)(m0 + rm) * DD + k8 * 8;
    lA[t] = ldsA + s * 8;
  }
#pragma unroll
  for (int t = 0; t < 4; ++t) {
    int s  = tid + t * 256;
    int rm = s >> 3;
    int k8 = (s & 7) ^ (rm & 7);
    gBH[t] = WtH + (size_t)(c0 + rm) * DD + k8 * 8;
    gBT[t] = WtT + (size_t)(c0 + rm) * DD + k8 * 8;
    lBH[t] = ldsBH + s * 8;
    lBT[t] = ldsBT + s * 8;
  }

  f32x4 accH[2][4], accT[2][4];
#pragma unroll
  for (int i = 0; i < 2; ++i)
#pragma unroll
    for (int j = 0; j < 4; ++j) {
      accH[i][j] = (f32x4){0.f, 0.f, 0.f, 0.f};
      accT[i][j] = (f32x4){0.f, 0.f, 0.f, 0.f};
    }

  for (int kb = 0; kb < 8; ++kb) {
    __syncthreads();                 // prior chunk's LDS reads complete
    const int ko = kb * 64;          // k advance in elements
#pragma unroll
    for (int t = 0; t < 2; ++t) async16(gA[t] + ko, lA[t]);
#pragma unroll
    for (int t = 0; t < 4; ++t) {
      async16(gBH[t] + ko, lBH[t]);
      async16(gBT[t] + ko, lBT[t]);
    }
    __syncthreads();                 // drains vmcnt: LDS filled

#pragma unroll
    for (int ks = 0; ks < 2; ++ks) {
      const int jj = ((((ks << 2) + q) ^ (mr & 7)) << 3); // u16 offset in row
      short8 a[2];
#pragma unroll
      for (int mt = 0; mt < 2; ++mt)
        a[mt] = *(const short8*)(ldsA + (wqm * 32 + mt * 16 + mr) * 64 + jj);
#pragma unroll
      for (int nt = 0; nt < 4; ++nt) {
        int nofs = (wqn * 64 + nt * 16 + mr) * 64 + jj;
        short8 bh = *(const short8*)(ldsBH + nofs);
        short8 bt = *(const short8*)(ldsBT + nofs);
#pragma unroll
        for (int mt = 0; mt < 2; ++mt) {
          accH[mt][nt] = __builtin_amdgcn_mfma_f32_16x16x32_bf16(a[mt], bh, accH[mt][nt], 0, 0, 0);
          accT[mt][nt] = __builtin_amdgcn_mfma_f32_16x16x32_bf16(a[mt], bt, accT[mt][nt], 0, 0, 0);
        }
      }
    }
  }

  // Epilogue. C/D layout: col = lane&15, row = (lane>>4)*4 + reg.
  const int b512 = bidx * DD;
#pragma unroll
  for (int nt = 0; nt < 4; ++nt) {
    const int gc = c0 + wqn * 64 + nt * 16 + mr;
    float hb = hbv[gc], tb = tbv[gc];
    float nsc = 0.f, h0c = 0.f;
    if (layer == 0) {
      hb += vH0[b512 + gc];
      tb += vT0[b512 + gc];
      h0c = h0[gc];
    }
    if (layer < 2) nsc = noise_s[b512 + gc];
#pragma unroll
    for (int mt = 0; mt < 2; ++mt) {
      const int gmb = m0 + wqm * 32 + mt * 16 + q * 4;
#pragma unroll
      for (int r = 0; r < 4; ++r) {
        const size_t o = (size_t)(gmb + r) * DD + gc;
        float sp = (layer == 0) ? h0c : Sprev[o];
        float hg = tanhf(accH[mt][nt][r] + hb);
        float tg = 1.f / (1.f + __expf(-(accT[mt][nt][r] + tb)));
        float sn = (hg - sp) * tg + sp;
        if (layer < 2) {
          Snew[o] = sn;
          SDnew[o] = f2bf(sn * nsc);
        } else {
          Out[o] = sn;
        }
      }
    }
  }
}

// ---------------------------------------------------------------------------
extern "C" void kernel_launch(void* const* d_in, const int* in_sizes, int n_in,
                              void* d_out, int out_size, void* d_ws, size_t ws_size,
                              hipStream_t stream) {
  const float* h0  = (const float*)d_in[0];
  const float* seq = (const float*)d_in[1];
  const float* wH  = (const float*)d_in[2];
  const float* bH  = (const float*)d_in[3];
  const float* wT  = (const float*)d_in[4];
  const float* bT  = (const float*)d_in[5];
  const float* rHw = (const float*)d_in[6];
  const float* rHb = (const float*)d_in[7];
  const float* rTw = (const float*)d_in[8];
  const float* rTb = (const float*)d_in[9];
  float* out = (float*)d_out;

  char* ws = (char*)d_ws;
  float* noise_i = (float*)(ws);                       // 64 KB
  float* noise_s = (float*)(ws + (64 << 10));          // 64 KB
  float* vH0     = (float*)(ws + (128 << 10));         // 64 KB
  float* vT0     = (float*)(ws + (192 << 10));         // 64 KB
  u16* Wt    = (u16*)(ws + (256 << 10));               // 6 x 512 KB
  u16* Xbf   = (u16*)(ws + (4ull << 20));              // 64 MB (also SD1)
  u16* SD0   = (u16*)(ws + (68ull << 20));             // 64 MB

  noise_kernel<<<64, 256, 0, stream>>>(noise_i, noise_s);
  vec0_kernel<<<64, 256, 0, stream>>>(h0, noise_s, rHw, rHb, rTw, rTb, vH0, vT0);
  wt_all<<<384, 256, 0, stream>>>(wH, wT, rHw, rTw, Wt);
  xprep<<<M_TOT * DIN / 8 / 256, 256, 0, stream>>>(seq, noise_i, Xbf);

  const int NBLK = (M_TOT / 64) * (DD / 128);   // 4096
  // Layer 0: A=Xbf, S->out, SD->SD0
  layer_gemm<<<NBLK, NTHREADS, 0, stream>>>(
      Xbf, Wt + 0 * WSZ, Wt + 1 * WSZ, bH, bT, vH0, vT0, h0, noise_s,
      nullptr, out, SD0, nullptr, 0);
  // Layer 1: A=SD0, Sprev=out, S->out (in place, disjoint per element), SD->Xbf
  layer_gemm<<<NBLK, NTHREADS, 0, stream>>>(
      SD0, Wt + 2 * WSZ, Wt + 3 * WSZ, rHb + DD, rTb + DD, nullptr, nullptr, h0, noise_s,
      out, out, Xbf, nullptr, 1);
  // Layer 2: A=Xbf(SD1), Sprev=out, final -> out
  layer_gemm<<<NBLK, NTHREADS, 0, stream>>>(
      Xbf, Wt + 4 * WSZ, Wt + 5 * WSZ, rHb + 2 * DD, rTb + 2 * DD, nullptr, nullptr, h0, noise_s,
      out, nullptr, nullptr, out, 2);
}

// Round 10
// 687.663 us; speedup vs baseline: 1.5293x; 1.0498x over previous
//
#include <hip/hip_runtime.h>
#include <stdint.h>
#include <math.h>

// Problem constants (fixed by reference setup_inputs)
#define B_SZ   32
#define T_LEN  2048
#define DIN    512
#define DD     512
#define M_TOT  (B_SZ * T_LEN)   // 65536 rows
#define NTHREADS 256
#define WSZ    ((size_t)DD * DD)

typedef unsigned short u16;
typedef __attribute__((ext_vector_type(8))) short short8;
typedef __attribute__((ext_vector_type(4))) float f32x4;
typedef __attribute__((ext_vector_type(4))) unsigned int u32x4;

// ---------------------------------------------------------------------------
// fp32 -> bf16 round-to-nearest-even (scalar, for wt_all)
// ---------------------------------------------------------------------------
__device__ __forceinline__ u16 f2bf(float f) {
  uint32_t u = __float_as_uint(f);
  uint32_t r = (u + 0x7FFFu + ((u >> 16) & 1u)) >> 16;
  return (u16)r;
}

// packed f32x2 -> bf16x2 (RTNE), gfx950 hw instruction (no builtin)
__device__ __forceinline__ uint32_t cvtpk(float lo, float hi) {
  uint32_t r;
  asm("v_cvt_pk_bf16_f32 %0, %1, %2" : "=v"(r) : "v"(lo), "v"(hi));
  return r;
}

// async global->LDS, 16B per lane; LDS dest = wave-uniform base + lane*16
typedef const void __attribute__((address_space(1)))* as1cp;
typedef void __attribute__((address_space(3)))* as3p;
__device__ __forceinline__ void async16(const void* g, void* l) {
  __builtin_amdgcn_global_load_lds((as1cp)(uintptr_t)g,
                                   (as3p)(uint32_t)(uintptr_t)l, 16, 0, 0);
}

// ---------------------------------------------------------------------------
// Threefry-2x32 (20 rounds), bit-exact vs JAX's threefry2x32 primitive.
// ---------------------------------------------------------------------------
__device__ __forceinline__ uint32_t rotl32(uint32_t x, int n) {
  return (x << n) | (x >> (32 - n));
}

__device__ __forceinline__ void threefry2x32(uint32_t k0, uint32_t k1,
                                             uint32_t x0, uint32_t x1,
                                             uint32_t& o0, uint32_t& o1) {
  const uint32_t ks0 = k0, ks1 = k1, ks2 = k0 ^ k1 ^ 0x1BD11BDAu;
  uint32_t v0 = x0 + ks0, v1 = x1 + ks1;
#define TF_R(r) { v0 += v1; v1 = rotl32(v1, (r)); v1 ^= v0; }
  TF_R(13) TF_R(15) TF_R(26) TF_R(6)
  v0 += ks1; v1 += ks2 + 1u;
  TF_R(17) TF_R(29) TF_R(16) TF_R(24)
  v0 += ks2; v1 += ks0 + 2u;
  TF_R(13) TF_R(15) TF_R(26) TF_R(6)
  v0 += ks0; v1 += ks1 + 3u;
  TF_R(17) TF_R(29) TF_R(16) TF_R(24)
  v0 += ks1; v1 += ks2 + 4u;
  TF_R(13) TF_R(15) TF_R(26) TF_R(6)
  v0 += ks2; v1 += ks0 + 5u;
#undef TF_R
  o0 = v0; o1 = v1;
}

// ---------------------------------------------------------------------------
// Noise under JAX_ENABLE_X64=1 + partitionable threefry (verified round 3):
//   split (foldlike): keys[j] = threefry(key, (0, j))
//   bernoulli(p: python float -> f64): 64-bit draw bits64[i]=(b1<<32)|b2,
//   counter (0,i); u<0.25 <=> b1<0x40000000 ; u<0.75 <=> b1<0xC0000000
// ---------------------------------------------------------------------------
__global__ void noise_kernel(float* __restrict__ noise_i, float* __restrict__ noise_s) {
  int i = blockIdx.x * blockDim.x + threadIdx.x;
  if (i >= B_SZ * DIN) return;
  uint32_t k1a, k1b, k2a, k2b;
  threefry2x32(0u, 42u, 0u, 0u, k1a, k1b);
  threefry2x32(0u, 42u, 0u, 1u, k2a, k2b);
  uint32_t b1, b2;
  threefry2x32(k1a, k1b, 0u, (uint32_t)i, b1, b2);
  noise_i[i] = (b1 < 0x40000000u) ? 4.0f : 0.0f;
  threefry2x32(k2a, k2b, 0u, (uint32_t)i, b1, b2);
  noise_s[i] = (b1 < 0xC0000000u) ? (1.0f / 0.75f) : 0.0f;
}

// layer-0 state projections, exact fp32 (t-independent)
__global__ __launch_bounds__(256) void vec0_kernel(
    const float* __restrict__ h0, const float* __restrict__ noise_s,
    const float* __restrict__ rHw, const float* __restrict__ rHb,
    const float* __restrict__ rTw, const float* __restrict__ rTb,
    float* __restrict__ vH0, float* __restrict__ vT0) {
  __shared__ float sdv[DD];
  const int b = blockIdx.x >> 1;
  const int c = (blockIdx.x & 1) * 256 + threadIdx.x;
  for (int k = threadIdx.x; k < DD; k += 256)
    sdv[k] = h0[k] * noise_s[b * DD + k];
  __syncthreads();
  float aH = 0.f, aT = 0.f;
  for (int k = 0; k < DD; ++k) {
    float v = sdv[k];
    aH += v * rHw[(size_t)k * DD + c];
    aT += v * rTw[(size_t)k * DD + c];
  }
  vH0[b * DD + c] = aH + rHb[c];
  vT0[b * DD + c] = aT + rTb[c];
}

// ---------------------------------------------------------------------------
// Transpose+convert all six 512x512 fp32 W[k][n] -> bf16 Wt[n][k].
// Wt order: 0=wH 1=wT 2=r1H 3=r1T 4=r2H 5=r2T
// ---------------------------------------------------------------------------
__global__ __launch_bounds__(256) void wt_all(
    const float* __restrict__ wH, const float* __restrict__ wT,
    const float* __restrict__ rHw, const float* __restrict__ rTw,
    u16* __restrict__ Wt) {
  __shared__ float tile[64][68];
  const int which = blockIdx.x >> 6;
  const float* W;
  switch (which) {
    case 0: W = wH; break;
    case 1: W = wT; break;
    case 2: W = rHw + WSZ; break;
    case 3: W = rTw + WSZ; break;
    case 4: W = rHw + 2 * WSZ; break;
    default: W = rTw + 2 * WSZ; break;
  }
  u16* dst = Wt + (size_t)which * WSZ;
  const int tb = blockIdx.x & 63;
  const int kt = (tb >> 3) * 64;
  const int nt = (tb & 7) * 64;
  const int tid = threadIdx.x;
  {
    int r = tid >> 2;
#pragma unroll
    for (int u = 0; u < 4; ++u) {
      int c = ((tid & 3) + u * 4) * 4;
      float4 v = *(const float4*)(W + (size_t)(kt + r) * DD + nt + c);
      tile[r][c] = v.x; tile[r][c + 1] = v.y; tile[r][c + 2] = v.z; tile[r][c + 3] = v.w;
    }
  }
  __syncthreads();
  {
    int n = tid >> 2, seg = (tid & 3) * 16;
    u16 o[16];
#pragma unroll
    for (int u = 0; u < 16; ++u) o[u] = f2bf(tile[seg + u][n]);
    *(uint4*)(dst + (size_t)(nt + n) * DD + kt + seg) = *(const uint4*)o;
    *(uint4*)(dst + (size_t)(nt + n) * DD + kt + seg + 8) = *(const uint4*)(o + 8);
  }
}

// ---------------------------------------------------------------------------
// Fused layer GEMM v3: round-9 structure (64m x 128c, 4 waves, wave tile
// 32x64, acc 64 AGPR, 3 blocks/CU, BK=64, XOR-swizzled LDS, XCD swizzle)
// with REG-STAGED A: A is built on the fly from the fp32 state buffer
//   a = bf16(src * noise)   (identical math to the old xprep/SD prep)
// so the bf16 A/SD intermediate buffers and the xprep dispatch are gone.
// Per-layer traffic: fetch 128 MB fp32 src (+W via L2) + write 128 MB fp32.
// T14 ordering: A global loads issued BEFORE the B async16s -> the cvt's
// implicit vmcnt wait covers only A, leaving B loads in flight; the chunk
// barrier drains the rest.
// Epilogue sp = Asrc[o] (rows staged moments ago -> L2-hot); layer0 sp=h0.
// ---------------------------------------------------------------------------
__global__ __launch_bounds__(256, 3) void layer_gemm(
    const float* __restrict__ Asrc, // [65536][512] fp32 (seq or S_prev)
    const float* __restrict__ nzv,  // [32][512] noise vec (noise_i or noise_s)
    const u16* __restrict__ WtH,    // [512 n][512 k] bf16
    const u16* __restrict__ WtT,
    const float* __restrict__ hbv,  // [512]
    const float* __restrict__ tbv,  // [512]
    const float* __restrict__ vH0,  // [32][512] (layer0 only)
    const float* __restrict__ vT0,
    const float* __restrict__ h0,   // [512]
    float* __restrict__ Snew,       // [65536][512] fp32 out state
    int layer) {
  __shared__ u16 lds[20480];        // A:4096, BH:8192, BT:8192 (40 KiB)
  __shared__ float nzl[DD];         // staged noise row (2 KiB)
  u16* ldsA  = lds;
  u16* ldsBH = lds + 4096;
  u16* ldsBT = lds + 12288;

  const int tid  = threadIdx.x;
  const int lane = tid & 63, wid = tid >> 6;
  // XCD swizzle: 4096 blocks, 8 XCDs, bijective chunked remap
  const int bid  = (blockIdx.x & 7) * 512 + (blockIdx.x >> 3);
  const int m0   = (bid >> 2) * 64;     // 1024 m-tiles
  const int c0   = (bid & 3) * 128;     // 4 c-tiles
  const int bidx = m0 >> 11;            // batch index (tile never crosses b)
  const int q  = lane >> 4, mr = lane & 15;
  const int wqm = wid >> 1, wqn = wid & 1;  // rows-half, cols-half

  // stage this batch's noise row into LDS (read via ds during A-staging)
  for (int k = tid; k < DD; k += 256) nzl[k] = nzv[bidx * DD + k];

  // A reg-staging addresses: slot s in {tid, tid+256}; slot s (16B bf16
  // granule) holds row = s>>3, k8 = (s&7)^(row&7)  [round-3-verified swizzle]
  const float* gAsrc[2]; u16* lAdst[2]; int nzofs[2];
#pragma unroll
  for (int t = 0; t < 2; ++t) {
    int s = tid + t * 256;
    int row = s >> 3;
    int k8 = (s & 7) ^ (row & 7);
    gAsrc[t] = Asrc + (size_t)(m0 + row) * DD + k8 * 8;
    lAdst[t] = ldsA + s * 8;
    nzofs[t] = k8 * 8;
  }
  // B staging addresses (async16, unchanged from round 9)
  const u16* gBH[4]; const u16* gBT[4];
  u16* lBH[4]; u16* lBT[4];
#pragma unroll
  for (int t = 0; t < 4; ++t) {
    int s  = tid + t * 256;
    int rm = s >> 3;
    int k8 = (s & 7) ^ (rm & 7);
    gBH[t] = WtH + (size_t)(c0 + rm) * DD + k8 * 8;
    gBT[t] = WtT + (size_t)(c0 + rm) * DD + k8 * 8;
    lBH[t] = ldsBH + s * 8;
    lBT[t] = ldsBT + s * 8;
  }

  f32x4 accH[2][4], accT[2][4];
#pragma unroll
  for (int i = 0; i < 2; ++i)
#pragma unroll
    for (int j = 0; j < 4; ++j) {
      accH[i][j] = (f32x4){0.f, 0.f, 0.f, 0.f};
      accT[i][j] = (f32x4){0.f, 0.f, 0.f, 0.f};
    }

  for (int kb = 0; kb < 8; ++kb) {
    __syncthreads();                 // prev chunk's LDS reads done (+nzl ready)
    const int ko = kb * 64;
    // 1) A fp32 loads first (vmcnt wait for these won't drain B)
    float4 av0[2], av1[2];
#pragma unroll
    for (int t = 0; t < 2; ++t) {
      av0[t] = *(const float4*)(gAsrc[t] + ko);
      av1[t] = *(const float4*)(gAsrc[t] + ko + 4);
    }
    // 2) B async16 (8 loads, stay in flight during A cvt)
#pragma unroll
    for (int t = 0; t < 4; ++t) {
      async16(gBH[t] + ko, lBH[t]);
      async16(gBT[t] + ko, lBT[t]);
    }
    // 3) A: multiply noise, pack to bf16, swizzled ds_write
#pragma unroll
    for (int t = 0; t < 2; ++t) {
      const float4 n0 = *(const float4*)&nzl[ko + nzofs[t]];
      const float4 n1 = *(const float4*)&nzl[ko + nzofs[t] + 4];
      u32x4 pk;
      pk.x = cvtpk(av0[t].x * n0.x, av0[t].y * n0.y);
      pk.y = cvtpk(av0[t].z * n0.z, av0[t].w * n0.w);
      pk.z = cvtpk(av1[t].x * n1.x, av1[t].y * n1.y);
      pk.w = cvtpk(av1[t].z * n1.z, av1[t].w * n1.w);
      *(u32x4*)lAdst[t] = pk;
    }
    __syncthreads();                 // drains vmcnt (B) + lgkm (A writes)

#pragma unroll
    for (int ks = 0; ks < 2; ++ks) {
      const int jj = ((((ks << 2) + q) ^ (mr & 7)) << 3); // u16 offset in row
      short8 a[2];
#pragma unroll
      for (int mt = 0; mt < 2; ++mt)
        a[mt] = *(const short8*)(ldsA + (wqm * 32 + mt * 16 + mr) * 64 + jj);
#pragma unroll
      for (int nt = 0; nt < 4; ++nt) {
        int nofs = (wqn * 64 + nt * 16 + mr) * 64 + jj;
        short8 bh = *(const short8*)(ldsBH + nofs);
        short8 bt = *(const short8*)(ldsBT + nofs);
#pragma unroll
        for (int mt = 0; mt < 2; ++mt) {
          accH[mt][nt] = __builtin_amdgcn_mfma_f32_16x16x32_bf16(a[mt], bh, accH[mt][nt], 0, 0, 0);
          accT[mt][nt] = __builtin_amdgcn_mfma_f32_16x16x32_bf16(a[mt], bt, accT[mt][nt], 0, 0, 0);
        }
      }
    }
  }

  // Epilogue. C/D layout: col = lane&15, row = (lane>>4)*4 + reg.
  const int b512 = bidx * DD;
#pragma unroll
  for (int nt = 0; nt < 4; ++nt) {
    const int gc = c0 + wqn * 64 + nt * 16 + mr;
    float hb = hbv[gc], tb = tbv[gc];
    float h0c = 0.f;
    if (layer == 0) {
      hb += vH0[b512 + gc];
      tb += vT0[b512 + gc];
      h0c = h0[gc];
    }
#pragma unroll
    for (int mt = 0; mt < 2; ++mt) {
      const int gmb = m0 + wqm * 32 + mt * 16 + q * 4;
#pragma unroll
      for (int r = 0; r < 4; ++r) {
        const size_t o = (size_t)(gmb + r) * DD + gc;
        float sp = (layer == 0) ? h0c : Asrc[o];   // L2-hot (staged above)
        float hg = tanhf(accH[mt][nt][r] + hb);
        float tg = 1.f / (1.f + __expf(-(accT[mt][nt][r] + tb)));
        Snew[o] = (hg - sp) * tg + sp;
      }
    }
  }
}

// ---------------------------------------------------------------------------
extern "C" void kernel_launch(void* const* d_in, const int* in_sizes, int n_in,
                              void* d_out, int out_size, void* d_ws, size_t ws_size,
                              hipStream_t stream) {
  const float* h0  = (const float*)d_in[0];
  const float* seq = (const float*)d_in[1];
  const float* wH  = (const float*)d_in[2];
  const float* bH  = (const float*)d_in[3];
  const float* wT  = (const float*)d_in[4];
  const float* bT  = (const float*)d_in[5];
  const float* rHw = (const float*)d_in[6];
  const float* rHb = (const float*)d_in[7];
  const float* rTw = (const float*)d_in[8];
  const float* rTb = (const float*)d_in[9];
  float* out = (float*)d_out;

  char* ws = (char*)d_ws;
  float* noise_i = (float*)(ws);                       // 64 KB
  float* noise_s = (float*)(ws + (64 << 10));          // 64 KB
  float* vH0     = (float*)(ws + (128 << 10));         // 64 KB
  float* vT0     = (float*)(ws + (192 << 10));         // 64 KB
  u16* Wt        = (u16*)(ws + (256 << 10));           // 6 x 512 KB
  float* Sbuf    = (float*)(ws + (4ull << 20));        // 128 MB fp32 state

  noise_kernel<<<64, 256, 0, stream>>>(noise_i, noise_s);
  vec0_kernel<<<64, 256, 0, stream>>>(h0, noise_s, rHw, rHb, rTw, rTb, vH0, vT0);
  wt_all<<<384, 256, 0, stream>>>(wH, wT, rHw, rTw, Wt);

  const int NBLK = (M_TOT / 64) * (DD / 128);   // 4096
  // Layer 0: A = seq*noise_i (reg-staged), sp = h0 -> out (s1)
  layer_gemm<<<NBLK, NTHREADS, 0, stream>>>(
      seq, noise_i, Wt + 0 * WSZ, Wt + 1 * WSZ, bH, bT, vH0, vT0, h0,
      out, 0);
  // Layer 1: A = out(s1)*noise_s, sp = out -> Sbuf (s2)
  layer_gemm<<<NBLK, NTHREADS, 0, stream>>>(
      out, noise_s, Wt + 2 * WSZ, Wt + 3 * WSZ, rHb + DD, rTb + DD, vH0, vT0, h0,
      Sbuf, 1);
  // Layer 2: A = Sbuf(s2)*noise_s, sp = Sbuf -> out (final)
  layer_gemm<<<NBLK, NTHREADS, 0, stream>>>(
      Sbuf, noise_s, Wt + 4 * WSZ, Wt + 5 * WSZ, rHb + 2 * DD, rTb + 2 * DD, vH0, vT0, h0,
      out, 2);
}

// Round 11
// 671.055 us; speedup vs baseline: 1.5672x; 1.0247x over previous
//
#include <hip/hip_runtime.h>
#include <stdint.h>
#include <math.h>

// Problem constants (fixed by reference setup_inputs)
#define B_SZ   32
#define T_LEN  2048
#define DIN    512
#define DD     512
#define M_TOT  (B_SZ * T_LEN)   // 65536 rows
#define NTHREADS 256
#define WSZ    ((size_t)DD * DD)

typedef unsigned short u16;
typedef __attribute__((ext_vector_type(8))) short short8;
typedef __attribute__((ext_vector_type(4))) float f32x4;
typedef __attribute__((ext_vector_type(4))) unsigned int u32x4;

// ---------------------------------------------------------------------------
// fp32 -> bf16 round-to-nearest-even (scalar, for wt_all)
// ---------------------------------------------------------------------------
__device__ __forceinline__ u16 f2bf(float f) {
  uint32_t u = __float_as_uint(f);
  uint32_t r = (u + 0x7FFFu + ((u >> 16) & 1u)) >> 16;
  return (u16)r;
}

// packed f32x2 -> bf16x2 (RTNE), gfx950 hw instruction (no builtin)
__device__ __forceinline__ uint32_t cvtpk(float lo, float hi) {
  uint32_t r;
  asm("v_cvt_pk_bf16_f32 %0, %1, %2" : "=v"(r) : "v"(lo), "v"(hi));
  return r;
}

// async global->LDS, 16B per lane; LDS dest = wave-uniform base + lane*16
typedef const void __attribute__((address_space(1)))* as1cp;
typedef void __attribute__((address_space(3)))* as3p;
__device__ __forceinline__ void async16(const void* g, void* l) {
  __builtin_amdgcn_global_load_lds((as1cp)(uintptr_t)g,
                                   (as3p)(uint32_t)(uintptr_t)l, 16, 0, 0);
}

__device__ __forceinline__ float sigm_fast(float x) {
  return 1.f / (1.f + __expf(-x));
}
__device__ __forceinline__ float tanh_fast(float x) {
  return 1.f - 2.f / (1.f + __expf(2.f * x));
}

// ---------------------------------------------------------------------------
// Threefry-2x32 (20 rounds), bit-exact vs JAX's threefry2x32 primitive.
// ---------------------------------------------------------------------------
__device__ __forceinline__ uint32_t rotl32(uint32_t x, int n) {
  return (x << n) | (x >> (32 - n));
}

__device__ __forceinline__ void threefry2x32(uint32_t k0, uint32_t k1,
                                             uint32_t x0, uint32_t x1,
                                             uint32_t& o0, uint32_t& o1) {
  const uint32_t ks0 = k0, ks1 = k1, ks2 = k0 ^ k1 ^ 0x1BD11BDAu;
  uint32_t v0 = x0 + ks0, v1 = x1 + ks1;
#define TF_R(r) { v0 += v1; v1 = rotl32(v1, (r)); v1 ^= v0; }
  TF_R(13) TF_R(15) TF_R(26) TF_R(6)
  v0 += ks1; v1 += ks2 + 1u;
  TF_R(17) TF_R(29) TF_R(16) TF_R(24)
  v0 += ks2; v1 += ks0 + 2u;
  TF_R(13) TF_R(15) TF_R(26) TF_R(6)
  v0 += ks0; v1 += ks1 + 3u;
  TF_R(17) TF_R(29) TF_R(16) TF_R(24)
  v0 += ks1; v1 += ks2 + 4u;
  TF_R(13) TF_R(15) TF_R(26) TF_R(6)
  v0 += ks2; v1 += ks0 + 5u;
#undef TF_R
  o0 = v0; o1 = v1;
}

// ---------------------------------------------------------------------------
// Noise under JAX_ENABLE_X64=1 + partitionable threefry (verified round 3):
//   split (foldlike): keys[j] = threefry(key, (0, j))
//   bernoulli(p: python float -> f64): 64-bit draw bits64[i]=(b1<<32)|b2,
//   counter (0,i); u<0.25 <=> b1<0x40000000 ; u<0.75 <=> b1<0xC0000000
// ---------------------------------------------------------------------------
__global__ void noise_kernel(float* __restrict__ noise_i, float* __restrict__ noise_s) {
  int i = blockIdx.x * blockDim.x + threadIdx.x;
  if (i >= B_SZ * DIN) return;
  uint32_t k1a, k1b, k2a, k2b;
  threefry2x32(0u, 42u, 0u, 0u, k1a, k1b);
  threefry2x32(0u, 42u, 0u, 1u, k2a, k2b);
  uint32_t b1, b2;
  threefry2x32(k1a, k1b, 0u, (uint32_t)i, b1, b2);
  noise_i[i] = (b1 < 0x40000000u) ? 4.0f : 0.0f;
  threefry2x32(k2a, k2b, 0u, (uint32_t)i, b1, b2);
  noise_s[i] = (b1 < 0xC0000000u) ? (1.0f / 0.75f) : 0.0f;
}

// layer-0 state projections, exact fp32 (t-independent)
__global__ __launch_bounds__(256) void vec0_kernel(
    const float* __restrict__ h0, const float* __restrict__ noise_s,
    const float* __restrict__ rHw, const float* __restrict__ rHb,
    const float* __restrict__ rTw, const float* __restrict__ rTb,
    float* __restrict__ vH0, float* __restrict__ vT0) {
  __shared__ float sdv[DD];
  const int b = blockIdx.x >> 1;
  const int c = (blockIdx.x & 1) * 256 + threadIdx.x;
  for (int k = threadIdx.x; k < DD; k += 256)
    sdv[k] = h0[k] * noise_s[b * DD + k];
  __syncthreads();
  float aH = 0.f, aT = 0.f;
  for (int k = 0; k < DD; ++k) {
    float v = sdv[k];
    aH += v * rHw[(size_t)k * DD + c];
    aT += v * rTw[(size_t)k * DD + c];
  }
  vH0[b * DD + c] = aH + rHb[c];
  vT0[b * DD + c] = aT + rTb[c];
}

// ---------------------------------------------------------------------------
// Transpose+convert all six 512x512 fp32 W[k][n] -> bf16 Wt[n][k].
// Wt order: 0=wH 1=wT 2=r1H 3=r1T 4=r2H 5=r2T
// ---------------------------------------------------------------------------
__global__ __launch_bounds__(256) void wt_all(
    const float* __restrict__ wH, const float* __restrict__ wT,
    const float* __restrict__ rHw, const float* __restrict__ rTw,
    u16* __restrict__ Wt) {
  __shared__ float tile[64][68];
  const int which = blockIdx.x >> 6;
  const float* W;
  switch (which) {
    case 0: W = wH; break;
    case 1: W = wT; break;
    case 2: W = rHw + WSZ; break;
    case 3: W = rTw + WSZ; break;
    case 4: W = rHw + 2 * WSZ; break;
    default: W = rTw + 2 * WSZ; break;
  }
  u16* dst = Wt + (size_t)which * WSZ;
  const int tb = blockIdx.x & 63;
  const int kt = (tb >> 3) * 64;
  const int nt = (tb & 7) * 64;
  const int tid = threadIdx.x;
  {
    int r = tid >> 2;
#pragma unroll
    for (int u = 0; u < 4; ++u) {
      int c = ((tid & 3) + u * 4) * 4;
      float4 v = *(const float4*)(W + (size_t)(kt + r) * DD + nt + c);
      tile[r][c] = v.x; tile[r][c + 1] = v.y; tile[r][c + 2] = v.z; tile[r][c + 3] = v.w;
    }
  }
  __syncthreads();
  {
    int n = tid >> 2, seg = (tid & 3) * 16;
    u16 o[16];
#pragma unroll
    for (int u = 0; u < 16; ++u) o[u] = f2bf(tile[seg + u][n]);
    *(uint4*)(dst + (size_t)(nt + n) * DD + kt + seg) = *(const uint4*)o;
    *(uint4*)(dst + (size_t)(nt + n) * DD + kt + seg + 8) = *(const uint4*)(o + 8);
  }
}

// ---------------------------------------------------------------------------
// Fused layer GEMM v4: round-10 structure (64m x 128c, 4 waves, 32x64 wave
// tile, acc 64 AGPR, 3 blocks/CU, BK=64, XOR-swizzled LDS, XCD swizzle,
// reg-staged A with inline noise*bf16) + CROSS-CHUNK A PREFETCH (T14):
//   - A loads for chunk kb+1 issue BEFORE chunk kb's MFMA phase and stay
//     in flight across it (16 VGPR); cvt+ds_write happen at the top of
//     chunk kb+1 (after the post-compute barrier -> single A buffer legal).
//   - pre-compute barrier uses COUNTED vmcnt(4): drains B's 8 async16,
//     leaves the 4 younger A-prefetch loads in flight. sched_barrier(0)
//     pins B-before-A issue order so the count is sound.
//   - post-compute barrier is a RAW s_barrier + lgkmcnt(0) only:
//     __syncthreads would drain vmcnt(0) and kill the A prefetch.
// Round-10's regression cause (A's HBM latency serial inside each chunk)
// is thereby removed while keeping its traffic win.
// Epilogue: fast tanh/sigmoid (validated rounds 5-7, same absmax).
// ---------------------------------------------------------------------------
__global__ __launch_bounds__(256, 3) void layer_gemm(
    const float* __restrict__ Asrc, // [65536][512] fp32 (seq or S_prev)
    const float* __restrict__ nzv,  // [32][512] noise vec
    const u16* __restrict__ WtH,    // [512 n][512 k] bf16
    const u16* __restrict__ WtT,
    const float* __restrict__ hbv,  // [512]
    const float* __restrict__ tbv,  // [512]
    const float* __restrict__ vH0,  // [32][512] (layer0 only)
    const float* __restrict__ vT0,
    const float* __restrict__ h0,   // [512]
    float* __restrict__ Snew,       // [65536][512] fp32 out state
    int layer) {
  __shared__ u16 lds[20480];        // A:4096, BH:8192, BT:8192 (40 KiB)
  __shared__ float nzl[DD];         // staged noise row (2 KiB)
  u16* ldsA  = lds;
  u16* ldsBH = lds + 4096;
  u16* ldsBT = lds + 12288;

  const int tid  = threadIdx.x;
  const int lane = tid & 63, wid = tid >> 6;
  // XCD swizzle: 4096 blocks, 8 XCDs, bijective chunked remap
  const int bid  = (blockIdx.x & 7) * 512 + (blockIdx.x >> 3);
  const int m0   = (bid >> 2) * 64;     // 1024 m-tiles
  const int c0   = (bid & 3) * 128;     // 4 c-tiles
  const int bidx = m0 >> 11;            // batch index (tile never crosses b)
  const int q  = lane >> 4, mr = lane & 15;
  const int wqm = wid >> 1, wqn = wid & 1;  // rows-half, cols-half

  // stage this batch's noise row into LDS
  for (int k = tid; k < DD; k += 256) nzl[k] = nzv[bidx * DD + k];

  // A reg-staging addresses: slot s in {tid, tid+256}; slot s (16B bf16
  // granule) holds row = s>>3, k8 = (s&7)^(row&7)
  const float* gAsrc[2]; u16* lAdst[2]; int nzofs[2];
#pragma unroll
  for (int t = 0; t < 2; ++t) {
    int s = tid + t * 256;
    int row = s >> 3;
    int k8 = (s & 7) ^ (row & 7);
    gAsrc[t] = Asrc + (size_t)(m0 + row) * DD + k8 * 8;
    lAdst[t] = ldsA + s * 8;
    nzofs[t] = k8 * 8;
  }
  // B staging addresses (async16)
  const u16* gBH[4]; const u16* gBT[4];
  u16* lBH[4]; u16* lBT[4];
#pragma unroll
  for (int t = 0; t < 4; ++t) {
    int s  = tid + t * 256;
    int rm = s >> 3;
    int k8 = (s & 7) ^ (rm & 7);
    gBH[t] = WtH + (size_t)(c0 + rm) * DD + k8 * 8;
    gBT[t] = WtT + (size_t)(c0 + rm) * DD + k8 * 8;
    lBH[t] = ldsBH + s * 8;
    lBT[t] = ldsBT + s * 8;
  }

  f32x4 accH[2][4], accT[2][4];
#pragma unroll
  for (int i = 0; i < 2; ++i)
#pragma unroll
    for (int j = 0; j < 4; ++j) {
      accH[i][j] = (f32x4){0.f, 0.f, 0.f, 0.f};
      accT[i][j] = (f32x4){0.f, 0.f, 0.f, 0.f};
    }

  // Prologue: issue A(0) loads; nzl-visible barrier keeps them in flight
  float4 av0[2], av1[2];
#pragma unroll
  for (int t = 0; t < 2; ++t) {
    av0[t] = *(const float4*)(gAsrc[t]);
    av1[t] = *(const float4*)(gAsrc[t] + 4);
  }
  asm volatile("s_waitcnt lgkmcnt(0)" ::: "memory");  // nzl ds_writes done
  __builtin_amdgcn_s_barrier();

  for (int kb = 0; kb < 8; ++kb) {
    const int ko = kb * 64;
    // 1) cvt A(kb) from prefetched regs (latency was hidden under chunk
    //    kb-1's compute) + swizzled ds_write
#pragma unroll
    for (int t = 0; t < 2; ++t) {
      const float4 n0 = *(const float4*)&nzl[ko + nzofs[t]];
      const float4 n1 = *(const float4*)&nzl[ko + nzofs[t] + 4];
      u32x4 pk;
      pk.x = cvtpk(av0[t].x * n0.x, av0[t].y * n0.y);
      pk.y = cvtpk(av0[t].z * n0.z, av0[t].w * n0.w);
      pk.z = cvtpk(av1[t].x * n1.x, av1[t].y * n1.y);
      pk.w = cvtpk(av1[t].z * n1.z, av1[t].w * n1.w);
      *(u32x4*)lAdst[t] = pk;
    }
    // 2) B(kb) async16 (8 ops)
#pragma unroll
    for (int t = 0; t < 4; ++t) {
      async16(gBH[t] + ko, lBH[t]);
      async16(gBT[t] + ko, lBT[t]);
    }
    __builtin_amdgcn_sched_barrier(0);  // pin: B issued before A prefetch
    // 3) A(kb+1) prefetch into regs; flies across the whole compute phase
    if (kb < 7) {
#pragma unroll
      for (int t = 0; t < 2; ++t) {
        av0[t] = *(const float4*)(gAsrc[t] + ko + 64);
        av1[t] = *(const float4*)(gAsrc[t] + ko + 64 + 4);
      }
      __builtin_amdgcn_sched_barrier(0);  // pin: prefetch before waitcnt
      // drain B (8 oldest) only; 4 A-prefetch loads stay outstanding
      asm volatile("s_waitcnt vmcnt(4) lgkmcnt(0)" ::: "memory");
    } else {
      asm volatile("s_waitcnt vmcnt(0) lgkmcnt(0)" ::: "memory");
    }
    __builtin_amdgcn_s_barrier();       // LDS ready for all waves

    // 4) compute chunk kb
#pragma unroll
    for (int ks = 0; ks < 2; ++ks) {
      const int jj = ((((ks << 2) + q) ^ (mr & 7)) << 3); // u16 offset in row
      short8 a[2];
#pragma unroll
      for (int mt = 0; mt < 2; ++mt)
        a[mt] = *(const short8*)(ldsA + (wqm * 32 + mt * 16 + mr) * 64 + jj);
#pragma unroll
      for (int nt = 0; nt < 4; ++nt) {
        int nofs = (wqn * 64 + nt * 16 + mr) * 64 + jj;
        short8 bh = *(const short8*)(ldsBH + nofs);
        short8 bt = *(const short8*)(ldsBT + nofs);
#pragma unroll
        for (int mt = 0; mt < 2; ++mt) {
          accH[mt][nt] = __builtin_amdgcn_mfma_f32_16x16x32_bf16(a[mt], bh, accH[mt][nt], 0, 0, 0);
          accT[mt][nt] = __builtin_amdgcn_mfma_f32_16x16x32_bf16(a[mt], bt, accT[mt][nt], 0, 0, 0);
        }
      }
    }
    // 5) post-compute: RAW barrier (no vmcnt drain -> A prefetch survives).
    //    ds_reads were already consumed by MFMA (compiler-inserted lgkm
    //    waits), so lgkmcnt(0) here is cheap and guarantees read-complete
    //    before any wave overwrites the buffers next iteration.
    asm volatile("s_waitcnt lgkmcnt(0)" ::: "memory");
    __builtin_amdgcn_s_barrier();
  }

  // Epilogue. C/D layout: col = lane&15, row = (lane>>4)*4 + reg.
  const int b512 = bidx * DD;
#pragma unroll
  for (int nt = 0; nt < 4; ++nt) {
    const int gc = c0 + wqn * 64 + nt * 16 + mr;
    float hb = hbv[gc], tb = tbv[gc];
    float h0c = 0.f;
    if (layer == 0) {
      hb += vH0[b512 + gc];
      tb += vT0[b512 + gc];
      h0c = h0[gc];
    }
#pragma unroll
    for (int mt = 0; mt < 2; ++mt) {
      const int gmb = m0 + wqm * 32 + mt * 16 + q * 4;
#pragma unroll
      for (int r = 0; r < 4; ++r) {
        const size_t o = (size_t)(gmb + r) * DD + gc;
        float sp = (layer == 0) ? h0c : Asrc[o];   // L2-hot (staged above)
        float hg = tanh_fast(accH[mt][nt][r] + hb);
        float tg = sigm_fast(accT[mt][nt][r] + tb);
        Snew[o] = (hg - sp) * tg + sp;
      }
    }
  }
}

// ---------------------------------------------------------------------------
extern "C" void kernel_launch(void* const* d_in, const int* in_sizes, int n_in,
                              void* d_out, int out_size, void* d_ws, size_t ws_size,
                              hipStream_t stream) {
  const float* h0  = (const float*)d_in[0];
  const float* seq = (const float*)d_in[1];
  const float* wH  = (const float*)d_in[2];
  const float* bH  = (const float*)d_in[3];
  const float* wT  = (const float*)d_in[4];
  const float* bT  = (const float*)d_in[5];
  const float* rHw = (const float*)d_in[6];
  const float* rHb = (const float*)d_in[7];
  const float* rTw = (const float*)d_in[8];
  const float* rTb = (const float*)d_in[9];
  float* out = (float*)d_out;

  char* ws = (char*)d_ws;
  float* noise_i = (float*)(ws);                       // 64 KB
  float* noise_s = (float*)(ws + (64 << 10));          // 64 KB
  float* vH0     = (float*)(ws + (128 << 10));         // 64 KB
  float* vT0     = (float*)(ws + (192 << 10));         // 64 KB
  u16* Wt        = (u16*)(ws + (256 << 10));           // 6 x 512 KB
  float* Sbuf    = (float*)(ws + (4ull << 20));        // 128 MB fp32 state

  noise_kernel<<<64, 256, 0, stream>>>(noise_i, noise_s);
  vec0_kernel<<<64, 256, 0, stream>>>(h0, noise_s, rHw, rHb, rTw, rTb, vH0, vT0);
  wt_all<<<384, 256, 0, stream>>>(wH, wT, rHw, rTw, Wt);

  const int NBLK = (M_TOT / 64) * (DD / 128);   // 4096
  // Layer 0: A = seq*noise_i (reg-staged), sp = h0 -> out (s1)
  layer_gemm<<<NBLK, NTHREADS, 0, stream>>>(
      seq, noise_i, Wt + 0 * WSZ, Wt + 1 * WSZ, bH, bT, vH0, vT0, h0,
      out, 0);
  // Layer 1: A = out(s1)*noise_s, sp = out -> Sbuf (s2)
  layer_gemm<<<NBLK, NTHREADS, 0, stream>>>(
      out, noise_s, Wt + 2 * WSZ, Wt + 3 * WSZ, rHb + DD, rTb + DD, vH0, vT0, h0,
      Sbuf, 1);
  // Layer 2: A = Sbuf(s2)*noise_s, sp = Sbuf -> out (final)
  layer_gemm<<<NBLK, NTHREADS, 0, stream>>>(
      Sbuf, noise_s, Wt + 4 * WSZ, Wt + 5 * WSZ, rHb + 2 * DD, rTb + 2 * DD, vH0, vT0, h0,
      out, 2);
}